// Round 5
// baseline (131.550 us; speedup 1.0000x reference)
//
#include <hip/hip_runtime.h>

#define B_   4
#define S_   1024
#define D_   768
#define H_   12
#define HD_  64
#define NROW (B_*S_)          // 4096
#define RSTRIDE (H_*HD_)      // 768
#define NBH  (B_*H_)          // 48
#define LOG2E 1.44269504f

typedef __bf16 bf16_t;
typedef bf16_t bf16x8 __attribute__((ext_vector_type(8)));
typedef float  f32x4  __attribute__((ext_vector_type(4)));
typedef float  f32x16 __attribute__((ext_vector_type(16)));
typedef unsigned int u32x4 __attribute__((ext_vector_type(4)));

__device__ __forceinline__ unsigned short bf16b(float f){
  bf16_t b = (bf16_t)f;
  return __builtin_bit_cast(unsigned short, b);
}

__device__ __forceinline__ void gload16(const void* g, void* l){
  __builtin_amdgcn_global_load_lds(
      (const __attribute__((address_space(1))) void*)g,
      (__attribute__((address_space(3))) void*)l, 16, 0, 0);
}

__device__ __forceinline__ unsigned int cvtpk(float lo, float hi){
  unsigned int r;
  asm("v_cvt_pk_bf16_f32 %0, %1, %2" : "=v"(r) : "v"(lo), "v"(hi));
  return r;
}

__device__ __forceinline__ void plswap(unsigned int &a, unsigned int &b){
  asm volatile("v_permlane32_swap_b32 %0, %1" : "+v"(a), "+v"(b));
}

// ---------------- fused casts: all four f32->bf16 conversions in one launch ----------------
__global__ void cast_all(const float* __restrict__ s0, bf16_t* __restrict__ d0, int n0,
                         const float* __restrict__ s1, bf16_t* __restrict__ d1, int n1,
                         const float* __restrict__ s2, bf16_t* __restrict__ d2, int n2,
                         const float* __restrict__ s3, bf16_t* __restrict__ d3, int n3){
  int i = blockIdx.x*256 + threadIdx.x;
  const float* s; bf16_t* d; int off;
  if (i < n0){ s = s0; d = d0; off = i; }
  else if (i < n0+n1){ s = s1; d = d1; off = i - n0; }
  else if (i < n0+n1+n2){ s = s2; d = d2; off = i - n0 - n1; }
  else if (i < n0+n1+n2+n3){ s = s3; d = d3; off = i - n0 - n1 - n2; }
  else return;
  float4 v = reinterpret_cast<const float4*>(s)[off];
  ushort4 o;
  o.x = bf16b(v.x); o.y = bf16b(v.y); o.z = bf16b(v.z); o.w = bf16b(v.w);
  reinterpret_cast<ushort4*>(d)[off] = o;
}

// ---------------- RMSNorm + cast ----------------
__global__ void rmsnorm_kernel(const float* __restrict__ q, const float* __restrict__ w,
                               bf16_t* __restrict__ out){
  int row = blockIdx.x;
  const float* src = q + (size_t)row*D_;
  float vals[3]; float ss = 0.f;
#pragma unroll
  for (int i=0;i<3;i++){ float v = src[threadIdx.x + i*256]; vals[i]=v; ss += v*v; }
#pragma unroll
  for (int m=1;m<64;m<<=1) ss += __shfl_xor(ss, m, 64);
  __shared__ float red[4];
  if ((threadIdx.x & 63) == 0) red[threadIdx.x>>6] = ss;
  __syncthreads();
  float tot = red[0]+red[1]+red[2]+red[3];
  float rs = rsqrtf(tot*(1.0f/D_) + 1e-5f);
#pragma unroll
  for (int i=0;i<3;i++){
    int c = threadIdx.x + i*256;
    out[(size_t)row*D_ + c] = (bf16_t)(vals[i]*rs*w[c]);
  }
}

// ---------------- RoPE (ND mixed) + head-pack + cast ----------------
__global__ void rope_kernel(const float* __restrict__ src, const int* __restrict__ pos,
                            const float* __restrict__ freqs, bf16_t* __restrict__ dst,
                            int srcStride, float outScale){
  int idx = blockIdx.x*256 + threadIdx.x;
  if (idx >= NROW*H_*(HD_/2)) return;
  int row = idx / (H_*HD_/2);
  int rem = idx % (H_*HD_/2);
  int h = rem >> 5, f = rem & 31;
  float p0 = (float)pos[row*2+0], p1 = (float)pos[row*2+1];
  float ang = p0*freqs[h*32+f] + p1*freqs[H_*32 + h*32 + f];
  float s, c;
  __sincosf(ang, &s, &c);
  float2 x = *reinterpret_cast<const float2*>(src + (size_t)row*srcStride + h*HD_ + 2*f);
  float orr = (x.x*c - x.y*s)*outScale;
  float oi  = (x.x*s + x.y*c)*outScale;
  ushort2 o; o.x = bf16b(orr); o.y = bf16b(oi);
  *reinterpret_cast<ushort2*>(dst + (size_t)row*RSTRIDE + h*HD_ + 2*f) = o;
}

// ---------------- V transpose: kvp[:,768:1536] f32 -> vt[bh][d][s] bf16 ----------------
__global__ void transpose_v(const float* __restrict__ kvp, bf16_t* __restrict__ vt){
  int st = blockIdx.x;              // s-tile 0..15
  int bh = blockIdx.y;              // 0..47
  int b = bh / H_, h = bh % H_;
  __shared__ bf16_t T[64][66];
  int t = threadIdx.x;
  {
    int sl = t >> 2, dc = (t & 3)*16;
    const float* src = kvp + ((size_t)(b*S_ + st*64 + sl))*(2*D_) + D_ + h*HD_ + dc;
#pragma unroll
    for (int k=0;k<4;k++){
      float4 v = *reinterpret_cast<const float4*>(src + k*4);
      T[dc + k*4 + 0][sl] = (bf16_t)v.x;
      T[dc + k*4 + 1][sl] = (bf16_t)v.y;
      T[dc + k*4 + 2][sl] = (bf16_t)v.z;
      T[dc + k*4 + 3][sl] = (bf16_t)v.w;
    }
  }
  __syncthreads();
  {
    int d = t >> 2, sc = (t & 3)*16;
    bf16_t tmp[16];
#pragma unroll
    for (int i=0;i<16;i++) tmp[i] = T[d][sc+i];
    bf16_t* dst = vt + ((size_t)bh*HD_ + d)*S_ + st*64 + sc;
    *reinterpret_cast<bf16x8*>(dst)     = *reinterpret_cast<bf16x8*>(tmp);
    *reinterpret_cast<bf16x8*>(dst + 8) = *reinterpret_cast<bf16x8*>(tmp + 8);
  }
}

// ---------------- bf16 GEMM body: C[M,N] = A[M,K] * W[N,K]^T + bias ----------------
__device__ __forceinline__ void gemm_body(const bf16_t* __restrict__ A, const bf16_t* __restrict__ W,
                                          const float* __restrict__ bias, float* __restrict__ C,
                                          int N, int K, int row0, int col0,
                                          bf16_t* As, bf16_t* Bs){
  const int tid  = threadIdx.x;
  const int lane = tid & 63;
  const int wv   = tid >> 6;
  const int wr = wv >> 1, wc = wv & 1;
  const int l4 = lane >> 4, lm = lane & 15;

  f32x4 acc[4][4] = {};

  for (int kt = 0; kt < K; kt += 32){
#pragma unroll
    for (int i=0;i<2;i++){
      int c = i*256 + tid;
      int r = c >> 2, kc = c & 3;
      gload16(A + (size_t)(row0+r)*K + kt + kc*8, As + (size_t)(i*256 + wv*64)*8);
    }
#pragma unroll
    for (int i=0;i<2;i++){
      int c = i*256 + tid;
      int r = c >> 2, kc = c & 3;
      gload16(W + (size_t)(col0+r)*K + kt + kc*8, Bs + (size_t)(i*256 + wv*64)*8);
    }
    __syncthreads();

    bf16x8 af[4], bfr[4];
#pragma unroll
    for (int mi=0;mi<4;mi++)
      af[mi] = *reinterpret_cast<const bf16x8*>(As + (wr*64 + mi*16 + lm)*32 + l4*8);
#pragma unroll
    for (int ni=0;ni<4;ni++)
      bfr[ni] = *reinterpret_cast<const bf16x8*>(Bs + (wc*64 + ni*16 + lm)*32 + l4*8);
#pragma unroll
    for (int mi=0;mi<4;mi++)
#pragma unroll
      for (int ni=0;ni<4;ni++)
        acc[mi][ni] = __builtin_amdgcn_mfma_f32_16x16x32_bf16(af[mi], bfr[ni], acc[mi][ni], 0,0,0);
    __syncthreads();
  }

#pragma unroll
  for (int mi=0;mi<4;mi++){
#pragma unroll
    for (int ni=0;ni<4;ni++){
      int col = col0 + wc*64 + ni*16 + lm;
      float bv = bias[col];
#pragma unroll
      for (int j=0;j<4;j++){
        int row = row0 + wr*64 + mi*16 + l4*4 + j;
        C[(size_t)row*N + col] = acc[mi][ni][j] + bv;
      }
    }
  }
}

__global__ void gemm_kernel(const bf16_t* __restrict__ A, const bf16_t* __restrict__ W,
                            const float* __restrict__ bias, float* __restrict__ C,
                            int N, int K){
  __shared__ bf16_t As[128*32];
  __shared__ bf16_t Bs[128*32];
  gemm_body(A, W, bias, C, N, K, blockIdx.x*128, blockIdx.y*128, As, Bs);
}

// fused q-proj + kv-proj: 576 blocks, XCD-bijective remap
__global__ void gemm_qkv_kernel(const bf16_t* __restrict__ qn, const bf16_t* __restrict__ kvb,
                                const bf16_t* __restrict__ wq, const bf16_t* __restrict__ wkv,
                                const float* __restrict__ bq, const float* __restrict__ bkv,
                                float* __restrict__ qp, float* __restrict__ kvp){
  __shared__ bf16_t As[128*32];
  __shared__ bf16_t Bs[128*32];
  int l = (blockIdx.x & 7)*72 + (blockIdx.x >> 3);  // 576 = 8*72
  int x = l & 31, y = l >> 5;
  if (y < 6)
    gemm_body(qn,  wq,  bq,  qp,  D_,   D_, x*128, y*128,     As, Bs);
  else
    gemm_body(kvb, wkv, bkv, kvp, 2*D_, D_, x*128, (y-6)*128, As, Bs);
}

// ---------------- flash attention: NO LDS, direct-from-L2 operands ----------------
// 3072 blocks x 64 thr (1 wave). Wave owns 32 q rows x 512 keys (split-K=2).
// K/V are L2-resident (256 KB/head); operands loaded per-lane straight to VGPR.
// No barriers, no staging, no drain. q pre-scaled by log2e/8 -> p = exp2(s).
__global__ __launch_bounds__(64, 4)
void attn_kernel(const bf16_t* __restrict__ Qh, const bf16_t* __restrict__ Kh,
                 const bf16_t* __restrict__ Vt, bf16_t* __restrict__ Opart,
                 float* __restrict__ psums){
  const int lane = threadIdx.x & 63;
  const int hi = lane >> 5, lq = lane & 31;
  // XCD-chunked bijective remap: 3072 = 8*384 (6 heads per XCD)
  int l = ((int)blockIdx.x & 7)*384 + ((int)blockIdx.x >> 3);
  const int bh   = l >> 6;            // 0..47
  const int rem  = l & 63;
  const int half = rem & 1;
  const int qt   = rem >> 1;          // 0..31
  const int b = bh / H_, h = bh % H_;
  const size_t headoff = ((size_t)b*S_*H_ + h)*HD_;
  const int q0 = qt*32;

  // Q b-frags: qf[c][j] = Q[q0+lq][c*16 + hi*8 + j]
  bf16x8 qf[4];
  {
    const bf16_t* qrow = Qh + headoff + (size_t)(q0 + lq)*RSTRIDE + hi*8;
#pragma unroll
    for (int c=0;c<4;c++)
      qf[c] = *reinterpret_cast<const bf16x8*>(qrow + c*16);
  }

  const bf16_t* kbase = Kh + headoff + (size_t)(half*512 + lq)*RSTRIDE + hi*8;
  const bf16_t* vbase = Vt + (size_t)bh*HD_*S_ + half*512 + hi*8;

  float psum = 0.f;
  f32x16 acc_o[2] = {};   // [dt]

#pragma unroll 4
  for (int kt=0; kt<16; ++kt){
    // QK^T (swapped): accs[r] = S[key = kb + crow(r,hi)][q = q0+lq]
    const bf16_t* kp = kbase + (size_t)kt*32*RSTRIDE;
    f32x16 accs = {};
#pragma unroll
    for (int c=0;c<4;c++){
      bf16x8 kf = *reinterpret_cast<const bf16x8*>(kp + c*16);
      accs = __builtin_amdgcn_mfma_f32_32x32x16_bf16(kf, qf[c], accs, 0,0,0);
    }

    // softmax (no max; scores bounded) fully in-register
#pragma unroll
    for (int r=0;r<16;r++){
      float v = exp2f(accs[r]);
      accs[r] = v;
      psum += v;
    }
    // P -> A-frags via cvt_pk + permlane32_swap
    bf16x8 pa[2];
#pragma unroll
    for (int ks=0;ks<2;ks++){
      const int base = ks*8;
      unsigned int a0 = cvtpk(accs[base+0], accs[base+1]);
      unsigned int a1 = cvtpk(accs[base+2], accs[base+3]);
      unsigned int b0 = cvtpk(accs[base+4], accs[base+5]);
      unsigned int b1 = cvtpk(accs[base+6], accs[base+7]);
      plswap(a0, b0);
      plswap(a1, b1);
      u32x4 w; w[0]=a0; w[1]=a1; w[2]=b0; w[3]=b1;
      pa[ks] = __builtin_bit_cast(bf16x8, w);
    }

    // PV: acc_o[dt] += P * V   (V fragments direct from transposed-V in L2)
#pragma unroll
    for (int dt=0;dt<2;dt++){
      const bf16_t* vp = vbase + (size_t)(dt*32 + lq)*S_ + kt*32;
#pragma unroll
      for (int ks=0;ks<2;ks++){
        bf16x8 vf = *reinterpret_cast<const bf16x8*>(vp + ks*16);
        acc_o[dt] = __builtin_amdgcn_mfma_f32_32x32x16_bf16(pa[ks], vf, acc_o[dt], 0,0,0);
      }
    }
  }

  // epilogue: hi-pair psum reduce + unnormalized partial writes
  {
    float tot = psum + __shfl_xor(psum, 32, 64);
    if (lane < 32)
      psums[half*(NBH*S_) + bh*S_ + q0 + lq] = tot;
  }
  bf16_t* obase = Opart + (size_t)half*NROW*RSTRIDE + headoff;
#pragma unroll
  for (int dt=0;dt<2;dt++)
#pragma unroll
    for (int r=0;r<16;r++){
      int qq = q0 + (r&3) + 8*(r>>2) + 4*hi;
      obase[(size_t)qq*RSTRIDE + dt*32 + lq] = (bf16_t)acc_o[dt][r];
    }
}

// ---------------- merge the two split-K halves ----------------
__global__ void attn_merge(const bf16_t* __restrict__ Op, const float* __restrict__ ps,
                           bf16_t* __restrict__ Oh){
  int i = blockIdx.x*256 + threadIdx.x;
  if (i >= NROW*RSTRIDE/4) return;
  int e0 = i*4;
  int row = e0 / RSTRIDE;
  int col = e0 % RSTRIDE;
  int h = col >> 6;
  int b = row >> 10, s = row & (S_-1);
  int bhrow = (b*H_ + h)*S_ + s;
  float denom = ps[bhrow] + ps[NBH*S_ + bhrow];
  float inv = 1.0f / denom;
  float acc[4] = {0.f,0.f,0.f,0.f};
#pragma unroll
  for (int t=0;t<2;t++){
    ushort4 a = *reinterpret_cast<const ushort4*>(Op + (size_t)t*NROW*RSTRIDE + e0);
    acc[0] += (float)__builtin_bit_cast(bf16_t,a.x);
    acc[1] += (float)__builtin_bit_cast(bf16_t,a.y);
    acc[2] += (float)__builtin_bit_cast(bf16_t,a.z);
    acc[3] += (float)__builtin_bit_cast(bf16_t,a.w);
  }
  ushort4 o;
  o.x = bf16b(acc[0]*inv); o.y = bf16b(acc[1]*inv);
  o.z = bf16b(acc[2]*inv); o.w = bf16b(acc[3]*inv);
  *reinterpret_cast<ushort4*>(Oh + e0) = o;
}

// ---------------- launch ----------------
extern "C" void kernel_launch(void* const* d_in, const int* in_sizes, int n_in,
                              void* d_out, int out_size, void* d_ws, size_t ws_size,
                              hipStream_t stream) {
  const float* q      = (const float*)d_in[0];
  const float* kv     = (const float*)d_in[1];
  const int*   posq   = (const int*)d_in[2];
  const int*   posk   = (const int*)d_in[3];
  const float* w_norm = (const float*)d_in[4];
  const float* w_q    = (const float*)d_in[5];
  const float* b_q    = (const float*)d_in[6];
  const float* w_kv   = (const float*)d_in[7];
  const float* b_kv   = (const float*)d_in[8];
  const float* w_out  = (const float*)d_in[9];
  const float* b_out  = (const float*)d_in[10];
  const float* freqs  = (const float*)d_in[11];
  float* out = (float*)d_out;

  char* p = (char*)d_ws;
  bf16_t* qn   = (bf16_t*)p; p += (size_t)NROW*D_*2;
  bf16_t* kvb  = (bf16_t*)p; p += (size_t)NROW*D_*2;
  bf16_t* wqb  = (bf16_t*)p; p += (size_t)D_*D_*2;
  bf16_t* wkvb = (bf16_t*)p; p += (size_t)2*D_*D_*2;
  bf16_t* wob  = (bf16_t*)p; p += (size_t)D_*D_*2;
  bf16_t* qh   = (bf16_t*)p; p += (size_t)NROW*D_*2;
  bf16_t* kh   = (bf16_t*)p; p += (size_t)NROW*D_*2;
  bf16_t* vt   = (bf16_t*)p; p += (size_t)NBH*HD_*S_*2;
  bf16_t* oh   = (bf16_t*)p; p += (size_t)NROW*D_*2;
  float*  qp   = (float*)p;  p += (size_t)NROW*D_*4;
  float*  kvp  = (float*)p;  p += (size_t)NROW*2*D_*4;
  // dead-after-rope/transpose buffers reused for attention partials:
  bf16_t* opart = (bf16_t*)kvp;         // 2*4096*768 bf16 = 12.6 MB (in dead kvp)
  float*  psums = (float*)qp;           // 2*48*1024 f32 = 393 KB (in dead qp)

  cast_all<<<(1376256+255)/256, 256, 0, stream>>>(
      w_q,  wqb,  D_*D_/4,
      w_kv, wkvb, 2*D_*D_/4,
      w_out, wob, D_*D_/4,
      kv,   kvb,  NROW*D_/4);
  rmsnorm_kernel<<<NROW, 256, 0, stream>>>(q, w_norm, qn);
  gemm_qkv_kernel<<<576, 256, 0, stream>>>(qn, kvb, wqb, wkvb, b_q, b_kv, qp, kvp);
  // q scale = 1/sqrt(64) * log2(e) so attention uses exp2 with no rescale
  rope_kernel<<<(NROW*H_*32+255)/256, 256, 0, stream>>>(qp,  posq, freqs, qh, D_,   0.125f*LOG2E);
  rope_kernel<<<(NROW*H_*32+255)/256, 256, 0, stream>>>(kvp, posk, freqs, kh, 2*D_, 1.0f);
  transpose_v<<<dim3(16, NBH), 256, 0, stream>>>(kvp, vt);
  attn_kernel<<<3072, 64, 0, stream>>>(qh, kh, vt, opart, psums);
  attn_merge<<<(NROW*RSTRIDE/4+255)/256, 256, 0, stream>>>(opart, psums, oh);
  gemm_kernel<<<dim3(32, 6), 256, 0, stream>>>(oh, wob, b_out, out, D_, D_);
}

// Round 6
// 112.726 us; speedup vs baseline: 1.1670x; 1.1670x over previous
//
#include <hip/hip_runtime.h>

#define B_   4
#define S_   1024
#define D_   768
#define H_   12
#define HD_  64
#define NROW (B_*S_)          // 4096
#define RSTRIDE (H_*HD_)      // 768
#define NBH  (B_*H_)          // 48
#define LOG2E 1.44269504f

typedef __bf16 bf16_t;
typedef bf16_t bf16x8 __attribute__((ext_vector_type(8)));
typedef float  f32x4  __attribute__((ext_vector_type(4)));
typedef float  f32x16 __attribute__((ext_vector_type(16)));
typedef unsigned int u32x4 __attribute__((ext_vector_type(4)));

__device__ __forceinline__ unsigned short bf16b(float f){
  bf16_t b = (bf16_t)f;
  return __builtin_bit_cast(unsigned short, b);
}

__device__ __forceinline__ void gload16(const void* g, void* l){
  __builtin_amdgcn_global_load_lds(
      (const __attribute__((address_space(1))) void*)g,
      (__attribute__((address_space(3))) void*)l, 16, 0, 0);
}

__device__ __forceinline__ unsigned int cvtpk(float lo, float hi){
  unsigned int r;
  asm("v_cvt_pk_bf16_f32 %0, %1, %2" : "=v"(r) : "v"(lo), "v"(hi));
  return r;
}

__device__ __forceinline__ void plswap(unsigned int &a, unsigned int &b){
  asm volatile("v_permlane32_swap_b32 %0, %1" : "+v"(a), "+v"(b));
}

// ---------------- fused casts: all four f32->bf16 conversions in one launch ----------------
__global__ void cast_all(const float* __restrict__ s0, bf16_t* __restrict__ d0, int n0,
                         const float* __restrict__ s1, bf16_t* __restrict__ d1, int n1,
                         const float* __restrict__ s2, bf16_t* __restrict__ d2, int n2,
                         const float* __restrict__ s3, bf16_t* __restrict__ d3, int n3){
  int i = blockIdx.x*256 + threadIdx.x;
  const float* s; bf16_t* d; int off;
  if (i < n0){ s = s0; d = d0; off = i; }
  else if (i < n0+n1){ s = s1; d = d1; off = i - n0; }
  else if (i < n0+n1+n2){ s = s2; d = d2; off = i - n0 - n1; }
  else if (i < n0+n1+n2+n3){ s = s3; d = d3; off = i - n0 - n1 - n2; }
  else return;
  float4 v = reinterpret_cast<const float4*>(s)[off];
  ushort4 o;
  o.x = bf16b(v.x); o.y = bf16b(v.y); o.z = bf16b(v.z); o.w = bf16b(v.w);
  reinterpret_cast<ushort4*>(d)[off] = o;
}

// ---------------- RMSNorm + cast ----------------
__global__ void rmsnorm_kernel(const float* __restrict__ q, const float* __restrict__ w,
                               bf16_t* __restrict__ out){
  int row = blockIdx.x;
  const float* src = q + (size_t)row*D_;
  float vals[3]; float ss = 0.f;
#pragma unroll
  for (int i=0;i<3;i++){ float v = src[threadIdx.x + i*256]; vals[i]=v; ss += v*v; }
#pragma unroll
  for (int m=1;m<64;m<<=1) ss += __shfl_xor(ss, m, 64);
  __shared__ float red[4];
  if ((threadIdx.x & 63) == 0) red[threadIdx.x>>6] = ss;
  __syncthreads();
  float tot = red[0]+red[1]+red[2]+red[3];
  float rs = rsqrtf(tot*(1.0f/D_) + 1e-5f);
#pragma unroll
  for (int i=0;i<3;i++){
    int c = threadIdx.x + i*256;
    out[(size_t)row*D_ + c] = (bf16_t)(vals[i]*rs*w[c]);
  }
}

// ---------------- RoPE + pack into MFMA-fragment-major layout ----------------
// dstfrag[((bh*32 + tile)*4 + c)*512 + hi*256 + lq*8 + j] = X[b,s=tile*32+lq][h, d=c*16+hi*8+j]
__global__ void rope_frag(const float* __restrict__ src, const int* __restrict__ pos,
                          const float* __restrict__ freqs, bf16_t* __restrict__ dstfrag,
                          int srcStride, float outScale){
  int idx = blockIdx.x*256 + threadIdx.x;
  if (idx >= NROW*H_*(HD_/2)) return;
  int row = idx / (H_*32);        // b*1024 + s
  int rem = idx % (H_*32);
  int h = rem >> 5, f = rem & 31;
  float p0 = (float)pos[row*2+0], p1 = (float)pos[row*2+1];
  float ang = p0*freqs[h*32+f] + p1*freqs[H_*32 + h*32 + f];
  float s, c;
  __sincosf(ang, &s, &c);
  float2 x = *reinterpret_cast<const float2*>(src + (size_t)row*srcStride + h*HD_ + 2*f);
  float orr = (x.x*c - x.y*s)*outScale;
  float oi  = (x.x*s + x.y*c)*outScale;
  int bh   = (row >> 10)*H_ + h;
  int tile = (row & 1023) >> 5;
  int lq   = row & 31;
  int cc = f >> 3, hi = (f >> 2) & 1, j = (f & 3)*2;
  bf16_t* dst = dstfrag + (((size_t)(bh*32 + tile)*4 + cc)*512 + hi*256 + lq*8 + j);
  ushort2 o; o.x = bf16b(orr); o.y = bf16b(oi);
  *reinterpret_cast<ushort2*>(dst) = o;
}

// ---------------- V pack: kvp[:,768:1536] f32 -> B-operand fragments ----------------
// vfrag[(bh*32+kb)*2048 + dt*1024 + ks*512 + hi*256 + lq*8 + j]
//   = V[b, key=kb*32+ks*16+hi*8+j][h, d=dt*32+lq]
__global__ void transpose_v(const float* __restrict__ kvp, bf16_t* __restrict__ vfrag){
  int kb = blockIdx.x;              // 0..31
  int bh = blockIdx.y;              // 0..47
  int b = bh / H_, h = bh % H_;
  int t = threadIdx.x;
  int lq = t & 31, hi = (t >> 5) & 1, ks = (t >> 6) & 1, dt = t >> 7;
  const float* src = kvp + ((size_t)(b*S_ + kb*32 + ks*16 + hi*8))*(2*D_) + D_ + h*HD_ + dt*32 + lq;
  bf16_t tmp[8];
#pragma unroll
  for (int j=0;j<8;j++) tmp[j] = (bf16_t)src[(size_t)j*(2*D_)];
  *reinterpret_cast<bf16x8*>(vfrag + (size_t)(bh*32 + kb)*2048 + t*8) =
      *reinterpret_cast<bf16x8*>(tmp);
}

// ---------------- bf16 GEMM body: C[M,N] = A[M,K] * W[N,K]^T + bias ----------------
__device__ __forceinline__ void gemm_body(const bf16_t* __restrict__ A, const bf16_t* __restrict__ W,
                                          const float* __restrict__ bias, float* __restrict__ C,
                                          int N, int K, int row0, int col0,
                                          bf16_t* As, bf16_t* Bs){
  const int tid  = threadIdx.x;
  const int lane = tid & 63;
  const int wv   = tid >> 6;
  const int wr = wv >> 1, wc = wv & 1;
  const int l4 = lane >> 4, lm = lane & 15;

  f32x4 acc[4][4] = {};

  for (int kt = 0; kt < K; kt += 32){
#pragma unroll
    for (int i=0;i<2;i++){
      int c = i*256 + tid;
      int r = c >> 2, kc = c & 3;
      gload16(A + (size_t)(row0+r)*K + kt + kc*8, As + (size_t)(i*256 + wv*64)*8);
    }
#pragma unroll
    for (int i=0;i<2;i++){
      int c = i*256 + tid;
      int r = c >> 2, kc = c & 3;
      gload16(W + (size_t)(col0+r)*K + kt + kc*8, Bs + (size_t)(i*256 + wv*64)*8);
    }
    __syncthreads();

    bf16x8 af[4], bfr[4];
#pragma unroll
    for (int mi=0;mi<4;mi++)
      af[mi] = *reinterpret_cast<const bf16x8*>(As + (wr*64 + mi*16 + lm)*32 + l4*8);
#pragma unroll
    for (int ni=0;ni<4;ni++)
      bfr[ni] = *reinterpret_cast<const bf16x8*>(Bs + (wc*64 + ni*16 + lm)*32 + l4*8);
#pragma unroll
    for (int mi=0;mi<4;mi++)
#pragma unroll
      for (int ni=0;ni<4;ni++)
        acc[mi][ni] = __builtin_amdgcn_mfma_f32_16x16x32_bf16(af[mi], bfr[ni], acc[mi][ni], 0,0,0);
    __syncthreads();
  }

#pragma unroll
  for (int mi=0;mi<4;mi++){
#pragma unroll
    for (int ni=0;ni<4;ni++){
      int col = col0 + wc*64 + ni*16 + lm;
      float bv = bias[col];
#pragma unroll
      for (int j=0;j<4;j++){
        int row = row0 + wr*64 + mi*16 + l4*4 + j;
        C[(size_t)row*N + col] = acc[mi][ni][j] + bv;
      }
    }
  }
}

__global__ void gemm_kernel(const bf16_t* __restrict__ A, const bf16_t* __restrict__ W,
                            const float* __restrict__ bias, float* __restrict__ C,
                            int N, int K){
  __shared__ bf16_t As[128*32];
  __shared__ bf16_t Bs[128*32];
  gemm_body(A, W, bias, C, N, K, blockIdx.x*128, blockIdx.y*128, As, Bs);
}

// fused q-proj + kv-proj: 576 blocks, XCD-bijective remap
__global__ void gemm_qkv_kernel(const bf16_t* __restrict__ qn, const bf16_t* __restrict__ kvb,
                                const bf16_t* __restrict__ wq, const bf16_t* __restrict__ wkv,
                                const float* __restrict__ bq, const float* __restrict__ bkv,
                                float* __restrict__ qp, float* __restrict__ kvp){
  __shared__ bf16_t As[128*32];
  __shared__ bf16_t Bs[128*32];
  int l = (blockIdx.x & 7)*72 + (blockIdx.x >> 3);  // 576 = 8*72
  int x = l & 31, y = l >> 5;
  if (y < 6)
    gemm_body(qn,  wq,  bq,  qp,  D_,   D_, x*128, y*128,     As, Bs);
  else
    gemm_body(kvb, wkv, bkv, kvp, 2*D_, D_, x*128, (y-6)*128, As, Bs);
}

// ---------------- flash attention: no LDS, coalesced fragment streaming ----------------
// 768 blocks x 256 thr (4 independent waves, no barriers). Wave = 32 q x 512 keys.
// All operands pre-packed fragment-major: every load is base + lane*8 (1KB/instr).
// q pre-scaled by log2e/8 -> p = exp2(s); no max (scores bounded ~2.4).
__global__ __launch_bounds__(256, 3)
void attn_kernel(const bf16_t* __restrict__ Qf, const bf16_t* __restrict__ Kf,
                 const bf16_t* __restrict__ Vf, bf16_t* __restrict__ Opart,
                 float* __restrict__ psums){
  const int lane = threadIdx.x & 63;
  const int wv   = threadIdx.x >> 6;
  const int hi = lane >> 5, lq = lane & 31;
  // XCD-chunked bijective remap: 768 = 8*96
  int l = ((int)blockIdx.x & 7)*96 + ((int)blockIdx.x >> 3);
  const int bh   = l >> 4;            // 0..47
  const int rem  = l & 15;
  const int half = rem & 1;
  const int qt   = (rem >> 1)*4 + wv; // 0..31
  const int q0   = qt*32;
  const int b = bh / H_, h = bh % H_;
  const size_t headoff = ((size_t)b*S_*H_ + h)*HD_;

  // Q fragments (B-operand): coalesced
  bf16x8 qf[4];
  {
    const bf16_t* qp_ = Qf + (size_t)(bh*32 + qt)*4*512 + lane*8;
#pragma unroll
    for (int c=0;c<4;c++)
      qf[c] = *reinterpret_cast<const bf16x8*>(qp_ + c*512);
  }

  const bf16_t* kbase = Kf + (size_t)(bh*32 + half*16)*4*512 + lane*8;
  const bf16_t* vbase = Vf + (size_t)(bh*32 + half*16)*2048  + lane*8;

  float psum = 0.f;
  f32x16 acc_o[2] = {};   // [dt]

#pragma unroll 2
  for (int kt=0; kt<16; ++kt){
    // QK^T (swapped): C[key][q], key = crow(r,hi), q = q0+lq
    const bf16_t* kp = kbase + (size_t)kt*2048;
    f32x16 accs = {};
#pragma unroll
    for (int c=0;c<4;c++){
      bf16x8 kf = *reinterpret_cast<const bf16x8*>(kp + c*512);
      accs = __builtin_amdgcn_mfma_f32_32x32x16_bf16(kf, qf[c], accs, 0,0,0);
    }

    // softmax (no max; scores bounded) fully in-register
#pragma unroll
    for (int r=0;r<16;r++){
      float v = exp2f(accs[r]);
      accs[r] = v;
      psum += v;
    }
    // P -> A-frags via cvt_pk + permlane32_swap
    bf16x8 pa[2];
#pragma unroll
    for (int ks=0;ks<2;ks++){
      const int base = ks*8;
      unsigned int a0 = cvtpk(accs[base+0], accs[base+1]);
      unsigned int a1 = cvtpk(accs[base+2], accs[base+3]);
      unsigned int b0 = cvtpk(accs[base+4], accs[base+5]);
      unsigned int b1 = cvtpk(accs[base+6], accs[base+7]);
      plswap(a0, b0);
      plswap(a1, b1);
      u32x4 w; w[0]=a0; w[1]=a1; w[2]=b0; w[3]=b1;
      pa[ks] = __builtin_bit_cast(bf16x8, w);
    }

    // PV: acc_o[dt] += P * V (V fragments coalesced)
    const bf16_t* vp = vbase + (size_t)kt*2048;
#pragma unroll
    for (int dt=0;dt<2;dt++){
#pragma unroll
      for (int ks=0;ks<2;ks++){
        bf16x8 vf = *reinterpret_cast<const bf16x8*>(vp + (dt*2+ks)*512);
        acc_o[dt] = __builtin_amdgcn_mfma_f32_32x32x16_bf16(pa[ks], vf, acc_o[dt], 0,0,0);
      }
    }
  }

  // epilogue: hi-pair psum reduce + unnormalized partial writes
  {
    float tot = psum + __shfl_xor(psum, 32, 64);
    if (lane < 32)
      psums[half*(NBH*S_) + bh*S_ + q0 + lq] = tot;
  }
  bf16_t* obase = Opart + (size_t)half*NROW*RSTRIDE + headoff;
#pragma unroll
  for (int dt=0;dt<2;dt++)
#pragma unroll
    for (int r=0;r<16;r++){
      int qq = q0 + (r&3) + 8*(r>>2) + 4*hi;
      obase[(size_t)qq*RSTRIDE + dt*32 + lq] = (bf16_t)acc_o[dt][r];
    }
}

// ---------------- merge the two split-K halves ----------------
__global__ void attn_merge(const bf16_t* __restrict__ Op, const float* __restrict__ ps,
                           bf16_t* __restrict__ Oh){
  int i = blockIdx.x*256 + threadIdx.x;
  if (i >= NROW*RSTRIDE/4) return;
  int e0 = i*4;
  int row = e0 / RSTRIDE;
  int col = e0 % RSTRIDE;
  int h = col >> 6;
  int b = row >> 10, s = row & (S_-1);
  int bhrow = (b*H_ + h)*S_ + s;
  float denom = ps[bhrow] + ps[NBH*S_ + bhrow];
  float inv = 1.0f / denom;
  float acc[4] = {0.f,0.f,0.f,0.f};
#pragma unroll
  for (int t=0;t<2;t++){
    ushort4 a = *reinterpret_cast<const ushort4*>(Op + (size_t)t*NROW*RSTRIDE + e0);
    acc[0] += (float)__builtin_bit_cast(bf16_t,a.x);
    acc[1] += (float)__builtin_bit_cast(bf16_t,a.y);
    acc[2] += (float)__builtin_bit_cast(bf16_t,a.z);
    acc[3] += (float)__builtin_bit_cast(bf16_t,a.w);
  }
  ushort4 o;
  o.x = bf16b(acc[0]*inv); o.y = bf16b(acc[1]*inv);
  o.z = bf16b(acc[2]*inv); o.w = bf16b(acc[3]*inv);
  *reinterpret_cast<ushort4*>(Oh + e0) = o;
}

// ---------------- launch ----------------
extern "C" void kernel_launch(void* const* d_in, const int* in_sizes, int n_in,
                              void* d_out, int out_size, void* d_ws, size_t ws_size,
                              hipStream_t stream) {
  const float* q      = (const float*)d_in[0];
  const float* kv     = (const float*)d_in[1];
  const int*   posq   = (const int*)d_in[2];
  const int*   posk   = (const int*)d_in[3];
  const float* w_norm = (const float*)d_in[4];
  const float* w_q    = (const float*)d_in[5];
  const float* b_q    = (const float*)d_in[6];
  const float* w_kv   = (const float*)d_in[7];
  const float* b_kv   = (const float*)d_in[8];
  const float* w_out  = (const float*)d_in[9];
  const float* b_out  = (const float*)d_in[10];
  const float* freqs  = (const float*)d_in[11];
  float* out = (float*)d_out;

  char* p = (char*)d_ws;
  bf16_t* qn   = (bf16_t*)p; p += (size_t)NROW*D_*2;
  bf16_t* kvb  = (bf16_t*)p; p += (size_t)NROW*D_*2;
  bf16_t* wqb  = (bf16_t*)p; p += (size_t)D_*D_*2;
  bf16_t* wkvb = (bf16_t*)p; p += (size_t)2*D_*D_*2;
  bf16_t* wob  = (bf16_t*)p; p += (size_t)D_*D_*2;
  bf16_t* qh   = (bf16_t*)p; p += (size_t)NROW*D_*2;   // Q fragments
  bf16_t* kh   = (bf16_t*)p; p += (size_t)NROW*D_*2;   // K fragments
  bf16_t* vt   = (bf16_t*)p; p += (size_t)NBH*HD_*S_*2; // V fragments
  bf16_t* oh   = (bf16_t*)p; p += (size_t)NROW*D_*2;
  float*  qp   = (float*)p;  p += (size_t)NROW*D_*4;
  float*  kvp  = (float*)p;  p += (size_t)NROW*2*D_*4;
  // dead-after-rope/pack buffers reused for attention partials:
  bf16_t* opart = (bf16_t*)kvp;         // 2*4096*768 bf16 = 12.6 MB (in dead kvp)
  float*  psums = (float*)qp;           // 2*48*1024 f32 = 393 KB (in dead qp)

  cast_all<<<(1376256+255)/256, 256, 0, stream>>>(
      w_q,  wqb,  D_*D_/4,
      w_kv, wkvb, 2*D_*D_/4,
      w_out, wob, D_*D_/4,
      kv,   kvb,  NROW*D_/4);
  rmsnorm_kernel<<<NROW, 256, 0, stream>>>(q, w_norm, qn);
  gemm_qkv_kernel<<<576, 256, 0, stream>>>(qn, kvb, wqb, wkvb, b_q, b_kv, qp, kvp);
  // q scale = 1/sqrt(64) * log2(e) so attention uses exp2 with no rescale
  rope_frag<<<(NROW*H_*32+255)/256, 256, 0, stream>>>(qp,  posq, freqs, qh, D_,   0.125f*LOG2E);
  rope_frag<<<(NROW*H_*32+255)/256, 256, 0, stream>>>(kvp, posk, freqs, kh, 2*D_, 1.0f);
  transpose_v<<<dim3(32, NBH), 256, 0, stream>>>(kvp, vt);
  attn_kernel<<<768, 256, 0, stream>>>(qh, kh, vt, opart, psums);
  attn_merge<<<(NROW*RSTRIDE/4+255)/256, 256, 0, stream>>>(opart, psums, oh);
  gemm_kernel<<<dim3(32, 6), 256, 0, stream>>>(oh, wob, b_out, out, D_, D_);
}